// Round 1
// baseline (4693.430 us; speedup 1.0000x reference)
//
#include <hip/hip_runtime.h>
#include <hip/hip_bf16.h>

// Transformer block: B=32 T=512 C=512 H=8 D=64
// Round 1: correctness-first. bf16 intermediates, fp32-accumulate tiled GEMMs,
// fused per-row causal attention. MFMA migration planned for next rounds.

#define B_  32
#define T_  512
#define C_  512
#define H_  8
#define D_  64
#define BT  (B_*T_)      // 16384 rows
#define CF  2048         // 4*C

typedef __hip_bfloat16 bf16;

__device__ __forceinline__ float bf2f(bf16 x) { return __bfloat162float(x); }
__device__ __forceinline__ bf16  f2bf(float x){ return __float2bfloat16(x); }

// ---------------- LayerNorm: one block per row (C=512), 256 threads ----------
__global__ __launch_bounds__(256) void ln_kernel(const float* __restrict__ x,
                                                 const float* __restrict__ g,
                                                 const float* __restrict__ b,
                                                 bf16* __restrict__ out)
{
    const int row = blockIdx.x;
    const int tid = threadIdx.x;
    const float* xr = x + (size_t)row * C_;
    float v0 = xr[tid], v1 = xr[tid + 256];

    __shared__ float red[4];

    // mean
    float s = v0 + v1;
    #pragma unroll
    for (int off = 32; off > 0; off >>= 1) s += __shfl_down(s, off, 64);
    if ((tid & 63) == 0) red[tid >> 6] = s;
    __syncthreads();
    const float mean = (red[0] + red[1] + red[2] + red[3]) * (1.0f / C_);
    __syncthreads();

    // variance
    float d0 = v0 - mean, d1 = v1 - mean;
    float vs = d0 * d0 + d1 * d1;
    #pragma unroll
    for (int off = 32; off > 0; off >>= 1) vs += __shfl_down(vs, off, 64);
    if ((tid & 63) == 0) red[tid >> 6] = vs;
    __syncthreads();
    const float var  = (red[0] + red[1] + red[2] + red[3]) * (1.0f / C_);
    const float rstd = rsqrtf(var + 1e-5f);

    bf16* orow = out + (size_t)row * C_;
    orow[tid]       = f2bf(d0 * rstd * g[tid]       + b[tid]);
    orow[tid + 256] = f2bf(d1 * rstd * g[tid + 256] + b[tid + 256]);
}

// ---------------- Tiled GEMM: C[M,N] = A[M,K](bf16) * Bw[K,N](f32) -----------
// Tile 64x64, BK=16, 256 threads, 4x4 microtile per thread.
// QKV=true: Bw is (H, K, 64) per-head layout, output written to (B,H,T,D).
// Epilogue: +bias (if non-null), ReLU (template), +res[m*N+n] (if non-null).
template<int KDIM, bool QKV, bool RELU, bool OUT_BF16>
__global__ __launch_bounds__(256) void gemm_kernel(const bf16*  __restrict__ A,
                                                   const float* __restrict__ Bw,
                                                   const float* __restrict__ bias,
                                                   const float* __restrict__ res,
                                                   void* __restrict__ outp,
                                                   int N)
{
    __shared__ float As[16][64];   // [k][m]
    __shared__ float Bs[16][64];   // [k][n]

    const int m0 = blockIdx.y * 64;
    const int n0 = blockIdx.x * 64;
    const int tid = threadIdx.x;
    const int tx = tid & 15, ty = tid >> 4;

    // staging index maps
    const int am = tid >> 2;            // 0..63 row within tile
    const int ak = (tid & 3) * 4;       // 0,4,8,12
    const int bk = tid >> 4;            // 0..15
    const int bn = (tid & 15) * 4;      // 0..60

    float acc[4][4] = {};

    for (int k0 = 0; k0 < KDIM; k0 += 16) {
        // A: coalesced-ish 4xbf16 per thread, transpose into As[k][m]
        const bf16* ap = A + (size_t)(m0 + am) * KDIM + (k0 + ak);
        float a0 = bf2f(ap[0]), a1 = bf2f(ap[1]), a2 = bf2f(ap[2]), a3 = bf2f(ap[3]);

        // B: float4 per thread
        const float* bp = QKV
            ? (Bw + ((size_t)(n0 >> 6) * KDIM + (k0 + bk)) * 64 + bn)
            : (Bw + (size_t)(k0 + bk) * N + (n0 + bn));
        float4 bv = *(const float4*)bp;

        As[ak + 0][am] = a0;
        As[ak + 1][am] = a1;
        As[ak + 2][am] = a2;
        As[ak + 3][am] = a3;
        *(float4*)&Bs[bk][bn] = bv;
        __syncthreads();

        #pragma unroll
        for (int kk = 0; kk < 16; ++kk) {
            float4 av  = *(const float4*)&As[kk][ty * 4];
            float4 bvv = *(const float4*)&Bs[kk][tx * 4];
            float a[4] = {av.x, av.y, av.z, av.w};
            float bb[4] = {bvv.x, bvv.y, bvv.z, bvv.w};
            #pragma unroll
            for (int i = 0; i < 4; ++i)
                #pragma unroll
                for (int j = 0; j < 4; ++j)
                    acc[i][j] += a[i] * bb[j];
        }
        __syncthreads();
    }

    #pragma unroll
    for (int i = 0; i < 4; ++i) {
        const int m = m0 + ty * 4 + i;
        #pragma unroll
        for (int j = 0; j < 4; ++j) {
            const int n = n0 + tx * 4 + j;
            float v = acc[i][j];
            if (bias) v += bias[n];
            if (RELU) v = fmaxf(v, 0.0f);
            if (res)  v += res[(size_t)m * N + n];
            size_t oi;
            if (QKV) {
                const int bb = m >> 9, t = m & 511, hh = n >> 6, dd = n & 63;
                oi = (((size_t)((bb << 3) + hh)) * T_ + t) * 64 + dd;
            } else {
                oi = (size_t)m * N + n;
            }
            if (OUT_BF16) ((bf16*)outp)[oi] = f2bf(v);
            else          ((float*)outp)[oi] = v;
        }
    }
}

// ---------------- Fused causal attention: one block per (tq, b*h) ------------
// q,k,v in (B,H,T,D); o written in (B,T,C) concat-head layout.
__global__ __launch_bounds__(256) void attn_kernel(const bf16* __restrict__ q,
                                                   const bf16* __restrict__ kM,
                                                   const bf16* __restrict__ vM,
                                                   bf16* __restrict__ o)
{
    const int tq  = blockIdx.x;
    const int bh  = blockIdx.y;
    const int tid = threadIdx.x;

    __shared__ float qs[64];
    __shared__ float sc[512];
    __shared__ float red[4];
    __shared__ float oacc[4][64];

    const bf16* qrow = q + ((size_t)bh * T_ + tq) * 64;
    if (tid < 64) qs[tid] = bf2f(qrow[tid]);
    __syncthreads();

    const int L = tq + 1;
    const float scale = 0.04419417382415922f;  // C^-0.5 = 512^-0.5 (per reference!)

    for (int s = tid; s < L; s += 256) {
        const bf16* kr = kM + ((size_t)bh * T_ + s) * 64;
        float a = 0.0f;
        #pragma unroll
        for (int dd = 0; dd < 64; ++dd) a += qs[dd] * bf2f(kr[dd]);
        sc[s] = a * scale;
    }
    __syncthreads();

    // block max over sc[0..L)
    float mx = -1e30f;
    for (int s = tid; s < L; s += 256) mx = fmaxf(mx, sc[s]);
    #pragma unroll
    for (int off = 32; off > 0; off >>= 1) mx = fmaxf(mx, __shfl_down(mx, off, 64));
    if ((tid & 63) == 0) red[tid >> 6] = mx;
    __syncthreads();
    mx = fmaxf(fmaxf(red[0], red[1]), fmaxf(red[2], red[3]));
    __syncthreads();

    // exp + block sum
    float sum = 0.0f;
    for (int s = tid; s < L; s += 256) {
        float e = __expf(sc[s] - mx);
        sc[s] = e;
        sum += e;
    }
    #pragma unroll
    for (int off = 32; off > 0; off >>= 1) sum += __shfl_down(sum, off, 64);
    if ((tid & 63) == 0) red[tid >> 6] = sum;
    __syncthreads();
    const float inv = 1.0f / (red[0] + red[1] + red[2] + red[3]);

    // o[d] = sum_s p[s] * v[s][d]; 4 chunks over s, 64 lanes over d
    const int dd = tid & 63, ch = tid >> 6;
    float a = 0.0f;
    for (int s = ch; s < L; s += 4)
        a += sc[s] * bf2f(vM[((size_t)bh * T_ + s) * 64 + dd]);
    oacc[ch][dd] = a;
    __syncthreads();

    if (tid < 64) {
        const int b = bh >> 3, hh = bh & 7;
        float r = (oacc[0][tid] + oacc[1][tid] + oacc[2][tid] + oacc[3][tid]) * inv;
        o[((size_t)b * T_ + tq) * C_ + hh * 64 + tid] = f2bf(r);
    }
}

// -----------------------------------------------------------------------------
extern "C" void kernel_launch(void* const* d_in, const int* in_sizes, int n_in,
                              void* d_out, int out_size, void* d_ws, size_t ws_size,
                              hipStream_t stream)
{
    const float* x     = (const float*)d_in[0];
    const float* wq    = (const float*)d_in[1];
    const float* wk    = (const float*)d_in[2];
    const float* wv    = (const float*)d_in[3];
    const float* wproj = (const float*)d_in[4];
    const float* bproj = (const float*)d_in[5];
    const float* w1    = (const float*)d_in[6];
    const float* b1    = (const float*)d_in[7];
    const float* w2    = (const float*)d_in[8];
    const float* b2    = (const float*)d_in[9];
    const float* ln1g  = (const float*)d_in[10];
    const float* ln1b  = (const float*)d_in[11];
    const float* ln2g  = (const float*)d_in[12];
    const float* ln2b  = (const float*)d_in[13];

    // Workspace layout (128 MB total):
    //  [0,16M)    h   bf16    (reused later as part of mid)
    //  [16,32M)   q   bf16
    //  [32,48M)   k   bf16
    //  [48,64M)   v   bf16
    //  [0,64M)    mid bf16  (BT x 2048) -- reuses h/q/k/v after attention
    //  [64,80M)   o   bf16  (B,T,C layout)
    //  [80,112M)  x1  f32   (residual after proj)
    //  [112,128M) h2  bf16
    char* ws = (char*)d_ws;
    bf16*  h   = (bf16*)(ws + 0);
    bf16*  q   = (bf16*)(ws + ((size_t)16 << 20));
    bf16*  k   = (bf16*)(ws + ((size_t)32 << 20));
    bf16*  v   = (bf16*)(ws + ((size_t)48 << 20));
    bf16*  mid = (bf16*)(ws + 0);
    bf16*  o   = (bf16*)(ws + ((size_t)64 << 20));
    float* x1  = (float*)(ws + ((size_t)80 << 20));
    bf16*  h2  = (bf16*)(ws + ((size_t)112 << 20));

    // 1. h = LN1(x)
    ln_kernel<<<BT, 256, 0, stream>>>(x, ln1g, ln1b, h);

    // 2. q,k,v = h @ w{q,k,v}  (per-head weight layout)
    dim3 g8(8, BT / 64), g32(32, BT / 64);
    gemm_kernel<512, true,  false, true><<<g8, 256, 0, stream>>>(h, wq, nullptr, nullptr, q, 512);
    gemm_kernel<512, true,  false, true><<<g8, 256, 0, stream>>>(h, wk, nullptr, nullptr, k, 512);
    gemm_kernel<512, true,  false, true><<<g8, 256, 0, stream>>>(h, wv, nullptr, nullptr, v, 512);

    // 3. o = softmax(q k^T * C^-0.5, causal) @ v   -> (B,T,C)
    attn_kernel<<<dim3(T_, B_ * H_), 256, 0, stream>>>(q, k, v, o);

    // 4. x1 = x + o @ w_proj + b_proj
    gemm_kernel<512, false, false, false><<<g8, 256, 0, stream>>>(o, wproj, bproj, x, x1, 512);

    // 5. h2 = LN2(x1)
    ln_kernel<<<BT, 256, 0, stream>>>(x1, ln2g, ln2b, h2);

    // 6. mid = relu(h2 @ w1 + b1)
    gemm_kernel<512, false, true,  true><<<g32, 256, 0, stream>>>(h2, w1, b1, nullptr, mid, 2048);

    // 7. out = x1 + mid @ w2 + b2
    gemm_kernel<2048, false, false, false><<<g8, 256, 0, stream>>>(mid, w2, b2, x1, (float*)d_out, 512);
}

// Round 2
// 1485.593 us; speedup vs baseline: 3.1593x; 3.1593x over previous
//
#include <hip/hip_runtime.h>
#include <hip/hip_bf16.h>

// Transformer block: B=32 T=512 C=512 H=8 D=64
// Round 2: flash-style MFMA attention (16x16x32 bf16), V pre-transposed by the
// v-GEMM to (B,H,D,T). GEMMs/LN unchanged from round 1 (VALU, known-correct).

#define B_  32
#define T_  512
#define C_  512
#define H_  8
#define D_  64
#define BT  (B_*T_)      // 16384 rows
#define CF  2048         // 4*C

typedef __hip_bfloat16 bf16;
typedef __attribute__((ext_vector_type(8))) short bf16x8;   // 8 bf16 (4 VGPRs)
typedef __attribute__((ext_vector_type(4))) float f32x4;

__device__ __forceinline__ float bf2f(bf16 x) { return __bfloat162float(x); }
__device__ __forceinline__ bf16  f2bf(float x){ return __float2bfloat16(x); }
__device__ __forceinline__ short f2bf_bits(float f){
    bf16 h = __float2bfloat16(f);
    return *reinterpret_cast<short*>(&h);
}
__device__ __forceinline__ float bfbits2f(short s){
    unsigned u = ((unsigned)(unsigned short)s) << 16;
    return __uint_as_float(u);
}

// ---------------- LayerNorm: one block per row (C=512), 256 threads ----------
__global__ __launch_bounds__(256) void ln_kernel(const float* __restrict__ x,
                                                 const float* __restrict__ g,
                                                 const float* __restrict__ b,
                                                 bf16* __restrict__ out)
{
    const int row = blockIdx.x;
    const int tid = threadIdx.x;
    const float* xr = x + (size_t)row * C_;
    float v0 = xr[tid], v1 = xr[tid + 256];

    __shared__ float red[4];

    float s = v0 + v1;
    #pragma unroll
    for (int off = 32; off > 0; off >>= 1) s += __shfl_down(s, off, 64);
    if ((tid & 63) == 0) red[tid >> 6] = s;
    __syncthreads();
    const float mean = (red[0] + red[1] + red[2] + red[3]) * (1.0f / C_);
    __syncthreads();

    float d0 = v0 - mean, d1 = v1 - mean;
    float vs = d0 * d0 + d1 * d1;
    #pragma unroll
    for (int off = 32; off > 0; off >>= 1) vs += __shfl_down(vs, off, 64);
    if ((tid & 63) == 0) red[tid >> 6] = vs;
    __syncthreads();
    const float var  = (red[0] + red[1] + red[2] + red[3]) * (1.0f / C_);
    const float rstd = rsqrtf(var + 1e-5f);

    bf16* orow = out + (size_t)row * C_;
    orow[tid]       = f2bf(d0 * rstd * g[tid]       + b[tid]);
    orow[tid + 256] = f2bf(d1 * rstd * g[tid + 256] + b[tid + 256]);
}

// ---------------- Tiled GEMM: C[M,N] = A[M,K](bf16) * Bw[K,N](f32) -----------
// Tile 64x64, BK=16, 256 threads, 4x4 microtile per thread.
// QKV: Bw is (H, K, 64) per-head layout, output to (B,H,T,D).
// VT (implies QKV): microtile roles swapped so output (B,H,D,T) stays coalesced.
template<int KDIM, bool QKV, bool VT, bool RELU, bool OUT_BF16>
__global__ __launch_bounds__(256) void gemm_kernel(const bf16*  __restrict__ A,
                                                   const float* __restrict__ Bw,
                                                   const float* __restrict__ bias,
                                                   const float* __restrict__ res,
                                                   void* __restrict__ outp,
                                                   int N)
{
    __shared__ float As[16][64];   // [k][m]
    __shared__ float Bs[16][64];   // [k][n]

    const int m0 = blockIdx.y * 64;
    const int n0 = blockIdx.x * 64;
    const int tid = threadIdx.x;
    const int tx = tid & 15, ty = tid >> 4;
    const int rsel = VT ? tx : ty;   // indexes m
    const int csel = VT ? ty : tx;   // indexes n

    const int am = tid >> 2;
    const int ak = (tid & 3) * 4;
    const int bk = tid >> 4;
    const int bn = (tid & 15) * 4;

    float acc[4][4] = {};

    for (int k0 = 0; k0 < KDIM; k0 += 16) {
        const bf16* ap = A + (size_t)(m0 + am) * KDIM + (k0 + ak);
        float a0 = bf2f(ap[0]), a1 = bf2f(ap[1]), a2 = bf2f(ap[2]), a3 = bf2f(ap[3]);

        const float* bp = QKV
            ? (Bw + ((size_t)(n0 >> 6) * KDIM + (k0 + bk)) * 64 + bn)
            : (Bw + (size_t)(k0 + bk) * N + (n0 + bn));
        float4 bv = *(const float4*)bp;

        As[ak + 0][am] = a0;
        As[ak + 1][am] = a1;
        As[ak + 2][am] = a2;
        As[ak + 3][am] = a3;
        *(float4*)&Bs[bk][bn] = bv;
        __syncthreads();

        #pragma unroll
        for (int kk = 0; kk < 16; ++kk) {
            float4 av  = *(const float4*)&As[kk][rsel * 4];
            float4 bvv = *(const float4*)&Bs[kk][csel * 4];
            float a[4] = {av.x, av.y, av.z, av.w};
            float bb[4] = {bvv.x, bvv.y, bvv.z, bvv.w};
            #pragma unroll
            for (int i = 0; i < 4; ++i)
                #pragma unroll
                for (int j = 0; j < 4; ++j)
                    acc[i][j] += a[i] * bb[j];
        }
        __syncthreads();
    }

    #pragma unroll
    for (int i = 0; i < 4; ++i) {
        const int m = m0 + rsel * 4 + i;
        #pragma unroll
        for (int j = 0; j < 4; ++j) {
            const int n = n0 + csel * 4 + j;
            float v = acc[i][j];
            if (bias) v += bias[n];
            if (RELU) v = fmaxf(v, 0.0f);
            if (res)  v += res[(size_t)m * N + n];
            size_t oi;
            if (QKV) {
                const int bb = m >> 9, t = m & 511, hh = n >> 6, dd = n & 63;
                if (VT) oi = ((size_t)((bb << 3) + hh) * 64 + dd) * T_ + t;
                else    oi = (((size_t)((bb << 3) + hh)) * T_ + t) * 64 + dd;
            } else {
                oi = (size_t)m * N + n;
            }
            if (OUT_BF16) ((bf16*)outp)[oi] = f2bf(v);
            else          ((float*)outp)[oi] = v;
        }
    }
}

// ---------------- Flash attention: MFMA 16x16x32 bf16 ------------------------
// Block = (q-tile of 64, b*h). 4 waves x 16 queries. K tiles of 64 staged in
// LDS (stride 72 = conflict-free for both b128 staging writes and frag reads).
// q,k in (B,H,T,D); v pre-transposed (B,H,D,T); o written (B,T,C).
__global__ __launch_bounds__(256) void attn_kernel(const bf16* __restrict__ q,
                                                   const bf16* __restrict__ kM,
                                                   const bf16* __restrict__ vT,
                                                   bf16* __restrict__ o)
{
    __shared__ __align__(16) bf16 Ks[64][72];
    __shared__ __align__(16) bf16 Vt[64][72];
    __shared__ __align__(16) bf16 Pw[4][16][72];

    const int qt   = gridDim.x - 1 - blockIdx.x;  // big q-tiles dispatched first
    const int bh   = blockIdx.y;
    const int tid  = threadIdx.x;
    const int wave = tid >> 6, lane = tid & 63;
    const int l16  = lane & 15, quad = lane >> 4;
    const int q0   = qt * 64;
    const int qw   = q0 + wave * 16;

    // Q A-frags, pre-scaled by C^-0.5 (reference scales by n_embd, not head!)
    const float scale = 0.04419417382415922f;
    bf16x8 qa[2];
    #pragma unroll
    for (int c = 0; c < 2; ++c) {
        const bf16* qp = q + ((size_t)bh * T_ + qw + l16) * 64 + c * 32 + quad * 8;
        bf16x8 t = *(const bf16x8*)qp;
        #pragma unroll
        for (int j = 0; j < 8; ++j) t[j] = f2bf_bits(bfbits2f(t[j]) * scale);
        qa[c] = t;
    }

    float m_i[4], l_i[4];
    f32x4 Of[4];
    #pragma unroll
    for (int r = 0; r < 4; ++r) { m_i[r] = -1e30f; l_i[r] = 0.0f; }
    #pragma unroll
    for (int f = 0; f < 4; ++f) Of[f] = (f32x4){0.f, 0.f, 0.f, 0.f};

    for (int kt = 0; kt <= qt; ++kt) {
        const int k0 = kt * 64;
        __syncthreads();   // previous iteration's reads done before overwrite
        #pragma unroll
        for (int c2 = 0; c2 < 2; ++c2) {
            const int ch = tid + c2 * 256;
            const int row = ch >> 3, e8 = (ch & 7) * 8;
            *(uint4*)&Ks[row][e8] = *(const uint4*)(kM + ((size_t)bh * T_ + k0 + row) * 64 + e8);
            *(uint4*)&Vt[row][e8] = *(const uint4*)(vT + ((size_t)bh * 64 + row) * T_ + k0 + e8);
        }
        __syncthreads();

        // S[16q x 64k] = Q K^T  (C-layout: row=quad*4+r, col=kf*16+l16)
        f32x4 Sf[4];
        #pragma unroll
        for (int kf = 0; kf < 4; ++kf) {
            bf16x8 b0 = *(const bf16x8*)&Ks[kf * 16 + l16][quad * 8];
            bf16x8 b1 = *(const bf16x8*)&Ks[kf * 16 + l16][32 + quad * 8];
            f32x4 z = (f32x4){0.f, 0.f, 0.f, 0.f};
            z = __builtin_amdgcn_mfma_f32_16x16x32_bf16(qa[0], b0, z, 0, 0, 0);
            z = __builtin_amdgcn_mfma_f32_16x16x32_bf16(qa[1], b1, z, 0, 0, 0);
            Sf[kf] = z;
        }

        if (kt == qt) {  // causal mask on the diagonal tile only
            #pragma unroll
            for (int kf = 0; kf < 4; ++kf)
                #pragma unroll
                for (int r = 0; r < 4; ++r)
                    if (k0 + kf * 16 + l16 > qw + quad * 4 + r) Sf[kf][r] = -1e30f;
        }

        // online softmax
        float mnew[4], alpha[4];
        #pragma unroll
        for (int r = 0; r < 4; ++r) {
            float v = fmaxf(fmaxf(Sf[0][r], Sf[1][r]), fmaxf(Sf[2][r], Sf[3][r]));
            v = fmaxf(v, __shfl_xor(v, 1, 64));
            v = fmaxf(v, __shfl_xor(v, 2, 64));
            v = fmaxf(v, __shfl_xor(v, 4, 64));
            v = fmaxf(v, __shfl_xor(v, 8, 64));
            mnew[r]  = fmaxf(m_i[r], v);
            alpha[r] = __expf(m_i[r] - mnew[r]);
            m_i[r]   = mnew[r];
        }

        float rs[4] = {0.f, 0.f, 0.f, 0.f};
        #pragma unroll
        for (int kf = 0; kf < 4; ++kf) {
            #pragma unroll
            for (int r = 0; r < 4; ++r) {
                float p = __expf(Sf[kf][r] - mnew[r]);
                rs[r] += p;
                Pw[wave][quad * 4 + r][kf * 16 + l16] = f2bf(p);
            }
        }
        #pragma unroll
        for (int r = 0; r < 4; ++r) {
            rs[r] += __shfl_xor(rs[r], 1, 64);
            rs[r] += __shfl_xor(rs[r], 2, 64);
            rs[r] += __shfl_xor(rs[r], 4, 64);
            rs[r] += __shfl_xor(rs[r], 8, 64);
            l_i[r] = l_i[r] * alpha[r] + rs[r];
        }
        #pragma unroll
        for (int f = 0; f < 4; ++f)
            #pragma unroll
            for (int r = 0; r < 4; ++r)
                Of[f][r] *= alpha[r];

        // O += P V   (A = P rows from Pw, B^T = Vt rows)
        bf16x8 pa0 = *(const bf16x8*)&Pw[wave][l16][quad * 8];
        bf16x8 pa1 = *(const bf16x8*)&Pw[wave][l16][32 + quad * 8];
        #pragma unroll
        for (int f = 0; f < 4; ++f) {
            bf16x8 vb0 = *(const bf16x8*)&Vt[f * 16 + l16][quad * 8];
            bf16x8 vb1 = *(const bf16x8*)&Vt[f * 16 + l16][32 + quad * 8];
            Of[f] = __builtin_amdgcn_mfma_f32_16x16x32_bf16(pa0, vb0, Of[f], 0, 0, 0);
            Of[f] = __builtin_amdgcn_mfma_f32_16x16x32_bf16(pa1, vb1, Of[f], 0, 0, 0);
        }
    }

    // epilogue: O /= l, write (B,T,C) concat-head
    const int b = bh >> 3, hh = bh & 7;
    #pragma unroll
    for (int r = 0; r < 4; ++r) {
        const float inv = 1.0f / l_i[r];
        const int t = qw + quad * 4 + r;
        #pragma unroll
        for (int f = 0; f < 4; ++f)
            o[((size_t)b * T_ + t) * C_ + hh * 64 + f * 16 + l16] = f2bf(Of[f][r] * inv);
    }
}

// -----------------------------------------------------------------------------
extern "C" void kernel_launch(void* const* d_in, const int* in_sizes, int n_in,
                              void* d_out, int out_size, void* d_ws, size_t ws_size,
                              hipStream_t stream)
{
    const float* x     = (const float*)d_in[0];
    const float* wq    = (const float*)d_in[1];
    const float* wk    = (const float*)d_in[2];
    const float* wv    = (const float*)d_in[3];
    const float* wproj = (const float*)d_in[4];
    const float* bproj = (const float*)d_in[5];
    const float* w1    = (const float*)d_in[6];
    const float* b1    = (const float*)d_in[7];
    const float* w2    = (const float*)d_in[8];
    const float* b2    = (const float*)d_in[9];
    const float* ln1g  = (const float*)d_in[10];
    const float* ln1b  = (const float*)d_in[11];
    const float* ln2g  = (const float*)d_in[12];
    const float* ln2b  = (const float*)d_in[13];

    char* ws = (char*)d_ws;
    bf16*  h   = (bf16*)(ws + 0);
    bf16*  q   = (bf16*)(ws + ((size_t)16 << 20));
    bf16*  k   = (bf16*)(ws + ((size_t)32 << 20));
    bf16*  v   = (bf16*)(ws + ((size_t)48 << 20));   // (B,H,D,T) transposed
    bf16*  mid = (bf16*)(ws + 0);
    bf16*  o   = (bf16*)(ws + ((size_t)64 << 20));
    float* x1  = (float*)(ws + ((size_t)80 << 20));
    bf16*  h2  = (bf16*)(ws + ((size_t)112 << 20));

    // 1. h = LN1(x)
    ln_kernel<<<BT, 256, 0, stream>>>(x, ln1g, ln1b, h);

    // 2. q,k,v = h @ w{q,k,v}; v written transposed (B,H,D,T)
    dim3 g8(8, BT / 64), g32(32, BT / 64);
    gemm_kernel<512, true,  false, false, true><<<g8, 256, 0, stream>>>(h, wq, nullptr, nullptr, q, 512);
    gemm_kernel<512, true,  false, false, true><<<g8, 256, 0, stream>>>(h, wk, nullptr, nullptr, k, 512);
    gemm_kernel<512, true,  true,  false, true><<<g8, 256, 0, stream>>>(h, wv, nullptr, nullptr, v, 512);

    // 3. o = flash-attn(q,k,v) -> (B,T,C)
    attn_kernel<<<dim3(8, B_ * H_), 256, 0, stream>>>(q, k, v, o);

    // 4. x1 = x + o @ w_proj + b_proj
    gemm_kernel<512, false, false, false, false><<<g8, 256, 0, stream>>>(o, wproj, bproj, x, x1, 512);

    // 5. h2 = LN2(x1)
    ln_kernel<<<BT, 256, 0, stream>>>(x1, ln2g, ln2b, h2);

    // 6. mid = relu(h2 @ w1 + b1)
    gemm_kernel<512, false, false, true,  true><<<g32, 256, 0, stream>>>(h2, w1, b1, nullptr, mid, 2048);

    // 7. out = x1 + mid @ w2 + b2
    gemm_kernel<2048, false, false, false, false><<<g8, 256, 0, stream>>>(mid, w2, b2, x1, (float*)d_out, 512);
}

// Round 3
// 467.387 us; speedup vs baseline: 10.0418x; 3.1785x over previous
//
#include <hip/hip_runtime.h>
#include <hip/hip_bf16.h>

// Transformer block: B=32 T=512 C=512 H=8 D=64
// Round 3: all GEMMs -> MFMA (m97 structure: 128x128 tile, BK=32,
// global_load_lds width-16, XOR-swizzled LDS chunks). Weights transposed+cast
// to bf16 (N,K) once per launch. x1 lives in d_out. Attention/LN unchanged.

#define B_  32
#define T_  512
#define C_  512
#define H_  8
#define D_  64
#define BT  (B_*T_)      // 16384 rows
#define CF  2048         // 4*C

typedef __hip_bfloat16 bf16;
typedef __attribute__((ext_vector_type(8))) short bf16x8;   // 8 bf16 (4 VGPRs)
typedef __attribute__((ext_vector_type(4))) float f32x4;
typedef __attribute__((ext_vector_type(4))) short short4v;

__device__ __forceinline__ float bf2f(bf16 x) { return __bfloat162float(x); }
__device__ __forceinline__ bf16  f2bf(float x){ return __float2bfloat16(x); }
__device__ __forceinline__ short f2bf_bits(float f){
    bf16 h = __float2bfloat16(f);
    return *reinterpret_cast<short*>(&h);
}
__device__ __forceinline__ float bfbits2f(short s){
    unsigned u = ((unsigned)(unsigned short)s) << 16;
    return __uint_as_float(u);
}

#define AS_G __attribute__((address_space(1)))
#define AS_L __attribute__((address_space(3)))

// ---------------- Weight transpose+cast: W[K][N] f32 -> Wt[N][K] bf16 --------
// 64x64 tiles, 256 threads; blockIdx.z batches (per-head QKV weights).
__global__ __launch_bounds__(256) void transpose_w(const float* __restrict__ W,
                                                   bf16* __restrict__ Wt,
                                                   int K, int N, int bsin, int bsout)
{
    W  += (size_t)blockIdx.z * bsin;
    Wt += (size_t)blockIdx.z * bsout;
    __shared__ float t[64][65];
    const int n0 = blockIdx.x * 64, k0 = blockIdx.y * 64;
    const int tid = threadIdx.x;
    #pragma unroll
    for (int j = 0; j < 16; ++j) {
        const int e = j * 256 + tid, r = e >> 6, c = e & 63;
        t[r][c] = W[(size_t)(k0 + r) * N + n0 + c];
    }
    __syncthreads();
    #pragma unroll
    for (int j = 0; j < 16; ++j) {
        const int e = j * 256 + tid, n = e >> 6, kk = e & 63;
        Wt[(size_t)(n0 + n) * K + k0 + kk] = f2bf(t[kk][n]);
    }
}

// ---------------- LayerNorm: one block per row (C=512), 256 threads ----------
__global__ __launch_bounds__(256) void ln_kernel(const float* __restrict__ x,
                                                 const float* __restrict__ g,
                                                 const float* __restrict__ b,
                                                 bf16* __restrict__ out)
{
    const int row = blockIdx.x;
    const int tid = threadIdx.x;
    const float* xr = x + (size_t)row * C_;
    float v0 = xr[tid], v1 = xr[tid + 256];

    __shared__ float red[4];

    float s = v0 + v1;
    #pragma unroll
    for (int off = 32; off > 0; off >>= 1) s += __shfl_down(s, off, 64);
    if ((tid & 63) == 0) red[tid >> 6] = s;
    __syncthreads();
    const float mean = (red[0] + red[1] + red[2] + red[3]) * (1.0f / C_);
    __syncthreads();

    float d0 = v0 - mean, d1 = v1 - mean;
    float vs = d0 * d0 + d1 * d1;
    #pragma unroll
    for (int off = 32; off > 0; off >>= 1) vs += __shfl_down(vs, off, 64);
    if ((tid & 63) == 0) red[tid >> 6] = vs;
    __syncthreads();
    const float var  = (red[0] + red[1] + red[2] + red[3]) * (1.0f / C_);
    const float rstd = rsqrtf(var + 1e-5f);

    bf16* orow = out + (size_t)row * C_;
    orow[tid]       = f2bf(d0 * rstd * g[tid]       + b[tid]);
    orow[tid + 256] = f2bf(d1 * rstd * g[tid + 256] + b[tid + 256]);
}

// ---------------- MFMA GEMM: C[M,N] = A[M,K](bf16) * Bt[N,K](bf16)^T ---------
// 128x128 tile, BK=32, 256 threads = 4 waves (2x2 of 64x64).
// global_load_lds width 16; LDS 16B chunks XOR-swizzled (phys = log ^ ((row>>1)&3))
// so b128 fragment reads are 2-way-only on banks (free).
// QKV: output scatter to (B,H,T,D); VT: to (B,H,D,T) with 4-wide t packing.
template<bool QKV, bool VT, bool RELU, bool OUT_BF16>
__global__ __launch_bounds__(256) void mfma_gemm(const bf16* __restrict__ A,
                                                 const bf16* __restrict__ Bt,
                                                 const float* __restrict__ bias,
                                                 const float* __restrict__ res,
                                                 void* __restrict__ outp,
                                                 int N, int K)
{
    __shared__ __align__(16) bf16 As[128 * 32];
    __shared__ __align__(16) bf16 Bs[128 * 32];

    const int tid  = threadIdx.x;
    const int wave = tid >> 6, lane = tid & 63;
    const int l16  = lane & 15, quad = lane >> 4;
    const int wm   = wave >> 1, wn = wave & 1;
    const int tm   = blockIdx.y * 128, tn = blockIdx.x * 128;

    const int rowS = tid >> 2, pS = tid & 3;   // staging row/phys-chunk

    f32x4 acc[4][4];
    #pragma unroll
    for (int i = 0; i < 4; ++i)
        #pragma unroll
        for (int j = 0; j < 4; ++j) acc[i][j] = (f32x4){0.f, 0.f, 0.f, 0.f};

    for (int k0 = 0; k0 < K; k0 += 32) {
        __syncthreads();
        #pragma unroll
        for (int i = 0; i < 2; ++i) {
            const int row = rowS + i * 64;
            const int c = pS ^ ((row >> 1) & 3);            // logical chunk
            const bf16* ga = A  + (size_t)(tm + row) * K + k0 + c * 8;
            const bf16* gb = Bt + (size_t)(tn + row) * K + k0 + c * 8;
            __builtin_amdgcn_global_load_lds((const AS_G void*)ga,
                                             (AS_L void*)&As[(i * 256 + tid) * 8], 16, 0, 0);
            __builtin_amdgcn_global_load_lds((const AS_G void*)gb,
                                             (AS_L void*)&Bs[(i * 256 + tid) * 8], 16, 0, 0);
        }
        __syncthreads();

        bf16x8 af[4], bfr[4];
        #pragma unroll
        for (int mf = 0; mf < 4; ++mf) {
            const int r = wm * 64 + mf * 16 + l16;
            const int p = quad ^ ((r >> 1) & 3);
            af[mf] = *(const bf16x8*)&As[r * 32 + p * 8];
        }
        #pragma unroll
        for (int nf = 0; nf < 4; ++nf) {
            const int r = wn * 64 + nf * 16 + l16;
            const int p = quad ^ ((r >> 1) & 3);
            bfr[nf] = *(const bf16x8*)&Bs[r * 32 + p * 8];
        }
        #pragma unroll
        for (int mf = 0; mf < 4; ++mf)
            #pragma unroll
            for (int nf = 0; nf < 4; ++nf)
                acc[mf][nf] = __builtin_amdgcn_mfma_f32_16x16x32_bf16(af[mf], bfr[nf], acc[mf][nf], 0, 0, 0);
    }

    // epilogue (C layout: row = quad*4+r, col = l16)
    #pragma unroll
    for (int mf = 0; mf < 4; ++mf) {
        const int mb = tm + wm * 64 + mf * 16 + quad * 4;
        #pragma unroll
        for (int nf = 0; nf < 4; ++nf) {
            const int n = tn + wn * 64 + nf * 16 + l16;
            f32x4 a = acc[mf][nf];
            if (QKV) {
                const int bb = mb >> 9, hh = n >> 6, dd = n & 63;
                if (VT) {
                    const int t = mb & 511;
                    short4v pk;
                    #pragma unroll
                    for (int r = 0; r < 4; ++r) pk[r] = f2bf_bits(a[r]);
                    *(short4v*)&((bf16*)outp)[((size_t)(bb * 8 + hh) * 64 + dd) * 512 + t] = pk;
                } else {
                    #pragma unroll
                    for (int r = 0; r < 4; ++r) {
                        const int t = (mb & 511) + r;
                        ((bf16*)outp)[((size_t)(bb * 8 + hh) * 512 + t) * 64 + dd] = f2bf(a[r]);
                    }
                }
            } else {
                #pragma unroll
                for (int r = 0; r < 4; ++r) {
                    const int m = mb + r;
                    float v = a[r];
                    if (bias) v += bias[n];
                    if (RELU) v = fmaxf(v, 0.0f);
                    if (res)  v += res[(size_t)m * N + n];
                    if (OUT_BF16) ((bf16*)outp)[(size_t)m * N + n] = f2bf(v);
                    else          ((float*)outp)[(size_t)m * N + n] = v;
                }
            }
        }
    }
}

// ---------------- Flash attention: MFMA 16x16x32 bf16 (unchanged) ------------
__global__ __launch_bounds__(256) void attn_kernel(const bf16* __restrict__ q,
                                                   const bf16* __restrict__ kM,
                                                   const bf16* __restrict__ vT,
                                                   bf16* __restrict__ o)
{
    __shared__ __align__(16) bf16 Ks[64][72];
    __shared__ __align__(16) bf16 Vt[64][72];
    __shared__ __align__(16) bf16 Pw[4][16][72];

    const int qt   = gridDim.x - 1 - blockIdx.x;
    const int bh   = blockIdx.y;
    const int tid  = threadIdx.x;
    const int wave = tid >> 6, lane = tid & 63;
    const int l16  = lane & 15, quad = lane >> 4;
    const int qw   = qt * 64 + wave * 16;

    const float scale = 0.04419417382415922f;  // C^-0.5 (reference uses n_embd)
    bf16x8 qa[2];
    #pragma unroll
    for (int c = 0; c < 2; ++c) {
        const bf16* qp = q + ((size_t)bh * T_ + qw + l16) * 64 + c * 32 + quad * 8;
        bf16x8 t = *(const bf16x8*)qp;
        #pragma unroll
        for (int j = 0; j < 8; ++j) t[j] = f2bf_bits(bfbits2f(t[j]) * scale);
        qa[c] = t;
    }

    float m_i[4], l_i[4];
    f32x4 Of[4];
    #pragma unroll
    for (int r = 0; r < 4; ++r) { m_i[r] = -1e30f; l_i[r] = 0.0f; }
    #pragma unroll
    for (int f = 0; f < 4; ++f) Of[f] = (f32x4){0.f, 0.f, 0.f, 0.f};

    for (int kt = 0; kt <= qt; ++kt) {
        const int k0 = kt * 64;
        __syncthreads();
        #pragma unroll
        for (int c2 = 0; c2 < 2; ++c2) {
            const int ch = tid + c2 * 256;
            const int row = ch >> 3, e8 = (ch & 7) * 8;
            *(uint4*)&Ks[row][e8] = *(const uint4*)(kM + ((size_t)bh * T_ + k0 + row) * 64 + e8);
            *(uint4*)&Vt[row][e8] = *(const uint4*)(vT + ((size_t)bh * 64 + row) * T_ + k0 + e8);
        }
        __syncthreads();

        f32x4 Sf[4];
        #pragma unroll
        for (int kf = 0; kf < 4; ++kf) {
            bf16x8 b0 = *(const bf16x8*)&Ks[kf * 16 + l16][quad * 8];
            bf16x8 b1 = *(const bf16x8*)&Ks[kf * 16 + l16][32 + quad * 8];
            f32x4 z = (f32x4){0.f, 0.f, 0.f, 0.f};
            z = __builtin_amdgcn_mfma_f32_16x16x32_bf16(qa[0], b0, z, 0, 0, 0);
            z = __builtin_amdgcn_mfma_f32_16x16x32_bf16(qa[1], b1, z, 0, 0, 0);
            Sf[kf] = z;
        }

        if (kt == qt) {
            #pragma unroll
            for (int kf = 0; kf < 4; ++kf)
                #pragma unroll
                for (int r = 0; r < 4; ++r)
                    if (k0 + kf * 16 + l16 > qw + quad * 4 + r) Sf[kf][r] = -1e30f;
        }

        float mnew[4], alpha[4];
        #pragma unroll
        for (int r = 0; r < 4; ++r) {
            float v = fmaxf(fmaxf(Sf[0][r], Sf[1][r]), fmaxf(Sf[2][r], Sf[3][r]));
            v = fmaxf(v, __shfl_xor(v, 1, 64));
            v = fmaxf(v, __shfl_xor(v, 2, 64));
            v = fmaxf(v, __shfl_xor(v, 4, 64));
            v = fmaxf(v, __shfl_xor(v, 8, 64));
            mnew[r]  = fmaxf(m_i[r], v);
            alpha[r] = __expf(m_i[r] - mnew[r]);
            m_i[r]   = mnew[r];
        }

        float rs[4] = {0.f, 0.f, 0.f, 0.f};
        #pragma unroll
        for (int kf = 0; kf < 4; ++kf) {
            #pragma unroll
            for (int r = 0; r < 4; ++r) {
                float p = __expf(Sf[kf][r] - mnew[r]);
                rs[r] += p;
                Pw[wave][quad * 4 + r][kf * 16 + l16] = f2bf(p);
            }
        }
        #pragma unroll
        for (int r = 0; r < 4; ++r) {
            rs[r] += __shfl_xor(rs[r], 1, 64);
            rs[r] += __shfl_xor(rs[r], 2, 64);
            rs[r] += __shfl_xor(rs[r], 4, 64);
            rs[r] += __shfl_xor(rs[r], 8, 64);
            l_i[r] = l_i[r] * alpha[r] + rs[r];
        }
        #pragma unroll
        for (int f = 0; f < 4; ++f)
            #pragma unroll
            for (int r = 0; r < 4; ++r)
                Of[f][r] *= alpha[r];

        bf16x8 pa0 = *(const bf16x8*)&Pw[wave][l16][quad * 8];
        bf16x8 pa1 = *(const bf16x8*)&Pw[wave][l16][32 + quad * 8];
        #pragma unroll
        for (int f = 0; f < 4; ++f) {
            bf16x8 vb0 = *(const bf16x8*)&Vt[f * 16 + l16][quad * 8];
            bf16x8 vb1 = *(const bf16x8*)&Vt[f * 16 + l16][32 + quad * 8];
            Of[f] = __builtin_amdgcn_mfma_f32_16x16x32_bf16(pa0, vb0, Of[f], 0, 0, 0);
            Of[f] = __builtin_amdgcn_mfma_f32_16x16x32_bf16(pa1, vb1, Of[f], 0, 0, 0);
        }
    }

    const int b = bh >> 3, hh = bh & 7;
    #pragma unroll
    for (int r = 0; r < 4; ++r) {
        const float inv = 1.0f / l_i[r];
        const int t = qw + quad * 4 + r;
        #pragma unroll
        for (int f = 0; f < 4; ++f)
            o[((size_t)b * T_ + t) * C_ + hh * 64 + f * 16 + l16] = f2bf(Of[f][r] * inv);
    }
}

// -----------------------------------------------------------------------------
extern "C" void kernel_launch(void* const* d_in, const int* in_sizes, int n_in,
                              void* d_out, int out_size, void* d_ws, size_t ws_size,
                              hipStream_t stream)
{
    const float* x     = (const float*)d_in[0];
    const float* wq    = (const float*)d_in[1];
    const float* wk    = (const float*)d_in[2];
    const float* wv    = (const float*)d_in[3];
    const float* wproj = (const float*)d_in[4];
    const float* bproj = (const float*)d_in[5];
    const float* w1    = (const float*)d_in[6];
    const float* b1    = (const float*)d_in[7];
    const float* w2    = (const float*)d_in[8];
    const float* b2    = (const float*)d_in[9];
    const float* ln1g  = (const float*)d_in[10];
    const float* ln1b  = (const float*)d_in[11];
    const float* ln2g  = (const float*)d_in[12];
    const float* ln2b  = (const float*)d_in[13];

    // Workspace (<=112 MB of the >=128 MB ws):
    //  [0,64M)    h,q,k,v (16 MB each) -> later mid (BT x 2048 bf16)
    //  [64,80M)   o (B,T,C bf16)
    //  [80,96M)   h2 (bf16)
    //  [96,102M)  transposed weights (bf16): wqt,wkt,wvt,wprojt (0.5M each), w1t,w2t (2M each)
    //  x1 (f32) lives in d_out (same-thread read-modify-write in final epilogue)
    char* ws = (char*)d_ws;
    bf16*  h      = (bf16*)(ws + 0);
    bf16*  q      = (bf16*)(ws + ((size_t)16 << 20));
    bf16*  k      = (bf16*)(ws + ((size_t)32 << 20));
    bf16*  v      = (bf16*)(ws + ((size_t)48 << 20));   // (B,H,D,T)
    bf16*  mid    = (bf16*)(ws + 0);
    bf16*  o      = (bf16*)(ws + ((size_t)64 << 20));
    bf16*  h2     = (bf16*)(ws + ((size_t)80 << 20));
    bf16*  wqt    = (bf16*)(ws + ((size_t)96 << 20));
    bf16*  wkt    = (bf16*)(ws + ((size_t)96 << 20) + (512 << 10));
    bf16*  wvt    = (bf16*)(ws + ((size_t)96 << 20) + (1024 << 10));
    bf16*  wprojt = (bf16*)(ws + ((size_t)96 << 20) + (1536 << 10));
    bf16*  w1t    = (bf16*)(ws + ((size_t)98 << 20));
    bf16*  w2t    = (bf16*)(ws + ((size_t)100 << 20));
    float* x1     = (float*)d_out;

    // 0. weight transpose+cast: Bt[N][K] bf16
    transpose_w<<<dim3(1, 8, 8),  256, 0, stream>>>(wq,    wqt,    512,  64,  512*64, 64*512);
    transpose_w<<<dim3(1, 8, 8),  256, 0, stream>>>(wk,    wkt,    512,  64,  512*64, 64*512);
    transpose_w<<<dim3(1, 8, 8),  256, 0, stream>>>(wv,    wvt,    512,  64,  512*64, 64*512);
    transpose_w<<<dim3(8, 8, 1),  256, 0, stream>>>(wproj, wprojt, 512,  512, 0, 0);
    transpose_w<<<dim3(32, 8, 1), 256, 0, stream>>>(w1,    w1t,    512,  2048, 0, 0);
    transpose_w<<<dim3(8, 32, 1), 256, 0, stream>>>(w2,    w2t,    2048, 512, 0, 0);

    // 1. h = LN1(x)
    ln_kernel<<<BT, 256, 0, stream>>>(x, ln1g, ln1b, h);

    // 2. q,k,v = h @ w{q,k,v}; v -> (B,H,D,T)
    dim3 g4(4, BT / 128), g16(16, BT / 128);
    mfma_gemm<true,  false, false, true ><<<g4, 256, 0, stream>>>(h, wqt, nullptr, nullptr, q, 512, 512);
    mfma_gemm<true,  false, false, true ><<<g4, 256, 0, stream>>>(h, wkt, nullptr, nullptr, k, 512, 512);
    mfma_gemm<true,  true,  false, true ><<<g4, 256, 0, stream>>>(h, wvt, nullptr, nullptr, v, 512, 512);

    // 3. o = flash-attn(q,k,v) -> (B,T,C)
    attn_kernel<<<dim3(8, B_ * H_), 256, 0, stream>>>(q, k, v, o);

    // 4. x1 = x + o @ w_proj + b_proj   (x1 = d_out, f32)
    mfma_gemm<false, false, false, false><<<g4, 256, 0, stream>>>(o, wprojt, bproj, x, x1, 512, 512);

    // 5. h2 = LN2(x1)
    ln_kernel<<<BT, 256, 0, stream>>>(x1, ln2g, ln2b, h2);

    // 6. mid = relu(h2 @ w1 + b1)
    mfma_gemm<false, false, true,  true ><<<g16, 256, 0, stream>>>(h2, w1t, b1, nullptr, mid, 2048, 512);

    // 7. out = x1 + mid @ w2 + b2   (in-place on d_out)
    mfma_gemm<false, false, false, false><<<g4, 256, 0, stream>>>(mid, w2t, b2, x1, (float*)d_out, 512, 2048);
}

// Round 4
// 392.481 us; speedup vs baseline: 11.9584x; 1.1909x over previous
//
#include <hip/hip_runtime.h>
#include <hip/hip_bf16.h>

// Transformer block: B=32 T=512 C=512 H=8 D=64
// Round 4: GEMM -> BK=64 (half the barrier drains), C^T accumulation for
// vectorized epilogues, QKV merged into one N=1536 GEMM, all weight
// transposes in one launch. Attention/LN unchanged.

#define B_  32
#define T_  512
#define C_  512
#define H_  8
#define D_  64
#define BT  (B_*T_)      // 16384 rows
#define CF  2048         // 4*C

typedef __hip_bfloat16 bf16;
typedef __attribute__((ext_vector_type(8))) short bf16x8;   // 8 bf16 (4 VGPRs)
typedef __attribute__((ext_vector_type(4))) float f32x4;
typedef __attribute__((ext_vector_type(4))) short short4v;

__device__ __forceinline__ float bf2f(bf16 x) { return __bfloat162float(x); }
__device__ __forceinline__ bf16  f2bf(float x){ return __float2bfloat16(x); }
__device__ __forceinline__ short f2bf_bits(float f){
    bf16 h = __float2bfloat16(f);
    return *reinterpret_cast<short*>(&h);
}
__device__ __forceinline__ float bfbits2f(short s){
    unsigned u = ((unsigned)(unsigned short)s) << 16;
    return __uint_as_float(u);
}

#define AS_G __attribute__((address_space(1)))
#define AS_L __attribute__((address_space(3)))

// ---------------- All weight transposes in one launch ------------------------
// 768 x 64x64 tiles: [0,192) qkv heads, [192,256) proj, [256,512) w1, [512,768) w2.
// Output: contiguous bf16 Wt buffers: qkvt[1536][512] | projt[512][512] |
// w1t[2048][512] | w2t[512][2048].
__global__ __launch_bounds__(256) void transpose_all(const float* __restrict__ wq,
                                                     const float* __restrict__ wk,
                                                     const float* __restrict__ wv,
                                                     const float* __restrict__ wproj,
                                                     const float* __restrict__ w1,
                                                     const float* __restrict__ w2,
                                                     bf16* __restrict__ wt)
{
    const int t = blockIdx.x;
    const float* src; int K, Nn, k0, n0; size_t dstoff;
    if (t < 192) {
        const int which = t / 64, w = t % 64, hh = w >> 3, kt = w & 7;
        src = (which == 0 ? wq : which == 1 ? wk : wv) + (size_t)hh * 512 * 64;
        K = 512; Nn = 64; k0 = kt * 64; n0 = 0;
        dstoff = (size_t)(which * 512 + hh * 64) * 512;
    } else if (t < 256) {
        const int i = t - 192;
        src = wproj; K = 512; Nn = 512; n0 = (i & 7) * 64; k0 = (i >> 3) * 64;
        dstoff = (size_t)1536 * 512;
    } else if (t < 512) {
        const int i = t - 256;
        src = w1; K = 512; Nn = 2048; n0 = (i & 31) * 64; k0 = (i >> 5) * 64;
        dstoff = (size_t)2048 * 512;
    } else {
        const int i = t - 512;
        src = w2; K = 2048; Nn = 512; n0 = (i & 7) * 64; k0 = (i >> 3) * 64;
        dstoff = (size_t)2048 * 512 + (size_t)2048 * 512;
    }

    __shared__ float tl[64][65];
    const int tid = threadIdx.x;
    #pragma unroll
    for (int j = 0; j < 16; ++j) {
        const int e = j * 256 + tid, r = e >> 6, c = e & 63;
        tl[r][c] = src[(size_t)(k0 + r) * Nn + n0 + c];
    }
    __syncthreads();
    #pragma unroll
    for (int j = 0; j < 16; ++j) {
        const int e = j * 256 + tid, n = e >> 6, kk = e & 63;
        wt[dstoff + (size_t)(n0 + n) * K + k0 + kk] = f2bf(tl[kk][n]);
    }
}

// ---------------- LayerNorm: one block per row (C=512), 256 threads ----------
__global__ __launch_bounds__(256) void ln_kernel(const float* __restrict__ x,
                                                 const float* __restrict__ g,
                                                 const float* __restrict__ b,
                                                 bf16* __restrict__ out)
{
    const int row = blockIdx.x;
    const int tid = threadIdx.x;
    const float* xr = x + (size_t)row * C_;
    float v0 = xr[tid], v1 = xr[tid + 256];

    __shared__ float red[4];

    float s = v0 + v1;
    #pragma unroll
    for (int off = 32; off > 0; off >>= 1) s += __shfl_down(s, off, 64);
    if ((tid & 63) == 0) red[tid >> 6] = s;
    __syncthreads();
    const float mean = (red[0] + red[1] + red[2] + red[3]) * (1.0f / C_);
    __syncthreads();

    float d0 = v0 - mean, d1 = v1 - mean;
    float vs = d0 * d0 + d1 * d1;
    #pragma unroll
    for (int off = 32; off > 0; off >>= 1) vs += __shfl_down(vs, off, 64);
    if ((tid & 63) == 0) red[tid >> 6] = vs;
    __syncthreads();
    const float var  = (red[0] + red[1] + red[2] + red[3]) * (1.0f / C_);
    const float rstd = rsqrtf(var + 1e-5f);

    bf16* orow = out + (size_t)row * C_;
    orow[tid]       = f2bf(d0 * rstd * g[tid]       + b[tid]);
    orow[tid + 256] = f2bf(d1 * rstd * g[tid + 256] + b[tid + 256]);
}

// ---------------- MFMA GEMM: C[M,N] = A[M,K](bf16) * Bt[N,K](bf16)^T ---------
// 128x128 tile, BK=64, 256 threads = 4 waves (2x2 of 64x64).
// global_load_lds width 16; 16B chunks XOR-8 swizzled (phys = log ^ (row&7)).
// Default: C^T accumulation (mfma(b,a)) -> lane's 4 acc regs are 4 consecutive
// n -> packed stores + vector bias/res loads.
// QKV: N=1536, n>>9 routes to q/k (B,H,T,D; C^T, dd-packed) or v (B,H,D,T;
// normal orientation, t-packed). Block-uniform.
template<bool QKV, bool RELU, bool OUT_BF16>
__global__ __launch_bounds__(256, 3) void mfma_gemm(const bf16* __restrict__ A,
                                                    const bf16* __restrict__ Bt,
                                                    const float* __restrict__ bias,
                                                    const float* __restrict__ res,
                                                    void* __restrict__ outp,
                                                    int N, int K)
{
    __shared__ __align__(16) bf16 As[128 * 64];
    __shared__ __align__(16) bf16 Bs[128 * 64];

    const int tid  = threadIdx.x;
    const int wave = tid >> 6, lane = tid & 63;
    const int l16  = lane & 15, quad = lane >> 4;
    const int wm   = wave >> 1, wn = wave & 1;
    const int tm   = blockIdx.y * 128, tn = blockIdx.x * 128;
    const bool vblk = QKV && (tn >= 1024);     // v third of the merged QKV GEMM

    f32x4 acc[4][4];
    #pragma unroll
    for (int i = 0; i < 4; ++i)
        #pragma unroll
        for (int j = 0; j < 4; ++j) acc[i][j] = (f32x4){0.f, 0.f, 0.f, 0.f};

    for (int k0 = 0; k0 < K; k0 += 64) {
        __syncthreads();
        #pragma unroll
        for (int j = 0; j < 4; ++j) {
            const int g = j * 256 + tid;
            const int row = g >> 3, phys = g & 7;
            const int c = phys ^ (row & 7);          // logical 16B chunk
            __builtin_amdgcn_global_load_lds((const AS_G void*)(A  + (size_t)(tm + row) * K + k0 + c * 8),
                                             (AS_L void*)&As[(size_t)g * 8], 16, 0, 0);
            __builtin_amdgcn_global_load_lds((const AS_G void*)(Bt + (size_t)(tn + row) * K + k0 + c * 8),
                                             (AS_L void*)&Bs[(size_t)g * 8], 16, 0, 0);
        }
        __syncthreads();

        #pragma unroll
        for (int half = 0; half < 2; ++half) {
            bf16x8 af[4], bfr[4];
            #pragma unroll
            for (int mf = 0; mf < 4; ++mf) {
                const int r = wm * 64 + mf * 16 + l16;
                const int p = (half * 4 + quad) ^ (r & 7);
                af[mf] = *(const bf16x8*)&As[r * 64 + p * 8];
            }
            #pragma unroll
            for (int nf = 0; nf < 4; ++nf) {
                const int r = wn * 64 + nf * 16 + l16;
                const int p = (half * 4 + quad) ^ (r & 7);
                bfr[nf] = *(const bf16x8*)&Bs[r * 64 + p * 8];
            }
            if (vblk) {
                #pragma unroll
                for (int mf = 0; mf < 4; ++mf)
                    #pragma unroll
                    for (int nf = 0; nf < 4; ++nf)
                        acc[mf][nf] = __builtin_amdgcn_mfma_f32_16x16x32_bf16(af[mf], bfr[nf], acc[mf][nf], 0, 0, 0);
            } else {
                #pragma unroll
                for (int mf = 0; mf < 4; ++mf)
                    #pragma unroll
                    for (int nf = 0; nf < 4; ++nf)
                        acc[mf][nf] = __builtin_amdgcn_mfma_f32_16x16x32_bf16(bfr[nf], af[mf], acc[mf][nf], 0, 0, 0);
            }
        }
    }

    if (QKV) {
        bf16* qkv = (bf16*)outp;                 // q base; k at +8M elems, v at +16M
        if (!vblk) {
            const int which = tn >> 9;           // 0=q, 1=k
            bf16* dst = qkv + (size_t)which * (8u << 20);
            #pragma unroll
            for (int mf = 0; mf < 4; ++mf) {
                const int m = tm + wm * 64 + mf * 16 + l16;   // token (C^T: col=m)
                const int bb = m >> 9, t = m & 511;
                #pragma unroll
                for (int nf = 0; nf < 4; ++nf) {
                    const int nb = tn + wn * 64 + nf * 16 + quad * 4;
                    const int hh = (nb >> 6) & 7, dd = nb & 63;
                    short4v pk;
                    #pragma unroll
                    for (int r = 0; r < 4; ++r) pk[r] = f2bf_bits(acc[mf][nf][r]);
                    *(short4v*)&dst[((size_t)(bb * 8 + hh) * 512 + t) * 64 + dd] = pk;
                }
            }
        } else {
            bf16* dst = qkv + (size_t)2 * (8u << 20);
            #pragma unroll
            for (int mf = 0; mf < 4; ++mf) {
                const int mb = tm + wm * 64 + mf * 16 + quad * 4;   // token base
                const int bb = mb >> 9, t = mb & 511;
                #pragma unroll
                for (int nf = 0; nf < 4; ++nf) {
                    const int n = tn + wn * 64 + nf * 16 + l16;
                    const int hh = (n >> 6) & 7, dd = n & 63;
                    short4v pk;
                    #pragma unroll
                    for (int r = 0; r < 4; ++r) pk[r] = f2bf_bits(acc[mf][nf][r]);
                    *(short4v*)&dst[((size_t)(bb * 8 + hh) * 64 + dd) * 512 + t] = pk;
                }
            }
        }
    } else {
        #pragma unroll
        for (int mf = 0; mf < 4; ++mf) {
            const int m = tm + wm * 64 + mf * 16 + l16;             // C^T: col=m
            #pragma unroll
            for (int nf = 0; nf < 4; ++nf) {
                const int nb = tn + wn * 64 + nf * 16 + quad * 4;   // 4 consecutive n
                f32x4 a = acc[mf][nf];
                if (bias) a += *(const f32x4*)&bias[nb];
                if (RELU) {
                    #pragma unroll
                    for (int r = 0; r < 4; ++r) a[r] = fmaxf(a[r], 0.0f);
                }
                if (res)  a += *(const f32x4*)&res[(size_t)m * N + nb];
                if (OUT_BF16) {
                    short4v pk;
                    #pragma unroll
                    for (int r = 0; r < 4; ++r) pk[r] = f2bf_bits(a[r]);
                    *(short4v*)&((bf16*)outp)[(size_t)m * N + nb] = pk;
                } else {
                    *(f32x4*)&((float*)outp)[(size_t)m * N + nb] = a;
                }
            }
        }
    }
}

// ---------------- Flash attention: MFMA 16x16x32 bf16 (unchanged) ------------
__global__ __launch_bounds__(256) void attn_kernel(const bf16* __restrict__ q,
                                                   const bf16* __restrict__ kM,
                                                   const bf16* __restrict__ vT,
                                                   bf16* __restrict__ o)
{
    __shared__ __align__(16) bf16 Ks[64][72];
    __shared__ __align__(16) bf16 Vt[64][72];
    __shared__ __align__(16) bf16 Pw[4][16][72];

    const int qt   = gridDim.x - 1 - blockIdx.x;
    const int bh   = blockIdx.y;
    const int tid  = threadIdx.x;
    const int wave = tid >> 6, lane = tid & 63;
    const int l16  = lane & 15, quad = lane >> 4;
    const int qw   = qt * 64 + wave * 16;

    const float scale = 0.04419417382415922f;  // C^-0.5 (reference uses n_embd)
    bf16x8 qa[2];
    #pragma unroll
    for (int c = 0; c < 2; ++c) {
        const bf16* qp = q + ((size_t)bh * T_ + qw + l16) * 64 + c * 32 + quad * 8;
        bf16x8 t = *(const bf16x8*)qp;
        #pragma unroll
        for (int j = 0; j < 8; ++j) t[j] = f2bf_bits(bfbits2f(t[j]) * scale);
        qa[c] = t;
    }

    float m_i[4], l_i[4];
    f32x4 Of[4];
    #pragma unroll
    for (int r = 0; r < 4; ++r) { m_i[r] = -1e30f; l_i[r] = 0.0f; }
    #pragma unroll
    for (int f = 0; f < 4; ++f) Of[f] = (f32x4){0.f, 0.f, 0.f, 0.f};

    for (int kt = 0; kt <= qt; ++kt) {
        const int k0 = kt * 64;
        __syncthreads();
        #pragma unroll
        for (int c2 = 0; c2 < 2; ++c2) {
            const int ch = tid + c2 * 256;
            const int row = ch >> 3, e8 = (ch & 7) * 8;
            *(uint4*)&Ks[row][e8] = *(const uint4*)(kM + ((size_t)bh * T_ + k0 + row) * 64 + e8);
            *(uint4*)&Vt[row][e8] = *(const uint4*)(vT + ((size_t)bh * 64 + row) * T_ + k0 + e8);
        }
        __syncthreads();

        f32x4 Sf[4];
        #pragma unroll
        for (int kf = 0; kf < 4; ++kf) {
            bf16x8 b0 = *(const bf16x8*)&Ks[kf * 16 + l16][quad * 8];
            bf16x8 b1 = *(const bf16x8*)&Ks[kf * 16 + l16][32 + quad * 8];
            f32x4 z = (f32x4){0.f, 0.f, 0.f, 0.f};
            z = __builtin_amdgcn_mfma_f32_16x16x32_bf16(qa[0], b0, z, 0, 0, 0);
            z = __builtin_amdgcn_mfma_f32_16x16x32_bf16(qa[1], b1, z, 0, 0, 0);
            Sf[kf] = z;
        }

        if (kt == qt) {
            #pragma unroll
            for (int kf = 0; kf < 4; ++kf)
                #pragma unroll
                for (int r = 0; r < 4; ++r)
                    if (k0 + kf * 16 + l16 > qw + quad * 4 + r) Sf[kf][r] = -1e30f;
        }

        float mnew[4], alpha[4];
        #pragma unroll
        for (int r = 0; r < 4; ++r) {
            float v = fmaxf(fmaxf(Sf[0][r], Sf[1][r]), fmaxf(Sf[2][r], Sf[3][r]));
            v = fmaxf(v, __shfl_xor(v, 1, 64));
            v = fmaxf(v, __shfl_xor(v, 2, 64));
            v = fmaxf(v, __shfl_xor(v, 4, 64));
            v = fmaxf(v, __shfl_xor(v, 8, 64));
            mnew[r]  = fmaxf(m_i[r], v);
            alpha[r] = __expf(m_i[r] - mnew[r]);
            m_i[r]   = mnew[r];
        }

        float rs[4] = {0.f, 0.f, 0.f, 0.f};
        #pragma unroll
        for (int kf = 0; kf < 4; ++kf) {
            #pragma unroll
            for (int r = 0; r < 4; ++r) {
                float p = __expf(Sf[kf][r] - mnew[r]);
                rs[r] += p;
                Pw[wave][quad * 4 + r][kf * 16 + l16] = f2bf(p);
            }
        }
        #pragma unroll
        for (int r = 0; r < 4; ++r) {
            rs[r] += __shfl_xor(rs[r], 1, 64);
            rs[r] += __shfl_xor(rs[r], 2, 64);
            rs[r] += __shfl_xor(rs[r], 4, 64);
            rs[r] += __shfl_xor(rs[r], 8, 64);
            l_i[r] = l_i[r] * alpha[r] + rs[r];
        }
        #pragma unroll
        for (int f = 0; f < 4; ++f)
            #pragma unroll
            for (int r = 0; r < 4; ++r)
                Of[f][r] *= alpha[r];

        bf16x8 pa0 = *(const bf16x8*)&Pw[wave][l16][quad * 8];
        bf16x8 pa1 = *(const bf16x8*)&Pw[wave][l16][32 + quad * 8];
        #pragma unroll
        for (int f = 0; f < 4; ++f) {
            bf16x8 vb0 = *(const bf16x8*)&Vt[f * 16 + l16][quad * 8];
            bf16x8 vb1 = *(const bf16x8*)&Vt[f * 16 + l16][32 + quad * 8];
            Of[f] = __builtin_amdgcn_mfma_f32_16x16x32_bf16(pa0, vb0, Of[f], 0, 0, 0);
            Of[f] = __builtin_amdgcn_mfma_f32_16x16x32_bf16(pa1, vb1, Of[f], 0, 0, 0);
        }
    }

    const int b = bh >> 3, hh = bh & 7;
    #pragma unroll
    for (int r = 0; r < 4; ++r) {
        const float inv = 1.0f / l_i[r];
        const int t = qw + quad * 4 + r;
        #pragma unroll
        for (int f = 0; f < 4; ++f)
            o[((size_t)b * T_ + t) * C_ + hh * 64 + f * 16 + l16] = f2bf(Of[f][r] * inv);
    }
}

// -----------------------------------------------------------------------------
extern "C" void kernel_launch(void* const* d_in, const int* in_sizes, int n_in,
                              void* d_out, int out_size, void* d_ws, size_t ws_size,
                              hipStream_t stream)
{
    const float* x     = (const float*)d_in[0];
    const float* wq    = (const float*)d_in[1];
    const float* wk    = (const float*)d_in[2];
    const float* wv    = (const float*)d_in[3];
    const float* wproj = (const float*)d_in[4];
    const float* bproj = (const float*)d_in[5];
    const float* w1    = (const float*)d_in[6];
    const float* b1    = (const float*)d_in[7];
    const float* w2    = (const float*)d_in[8];
    const float* b2    = (const float*)d_in[9];
    const float* ln1g  = (const float*)d_in[10];
    const float* ln1b  = (const float*)d_in[11];
    const float* ln2g  = (const float*)d_in[12];
    const float* ln2b  = (const float*)d_in[13];

    // Workspace:
    //  [0,64M)    h,q,k,v (16 MB each; q/k/v contiguous for merged-QKV scatter)
    //             -> later mid (BT x 2048 bf16)
    //  [64,80M)   o (B,T,C bf16)
    //  [80,96M)   h2 (bf16)
    //  [96,102M)  Wt: qkvt[1536][512] | projt[512][512] | w1t[2048][512] | w2t[512][2048]
    //  x1 (f32) lives in d_out (same-thread RMW in final epilogue)
    char* ws = (char*)d_ws;
    bf16*  h    = (bf16*)(ws + 0);
    bf16*  q    = (bf16*)(ws + ((size_t)16 << 20));
    bf16*  k    = (bf16*)(ws + ((size_t)32 << 20));
    bf16*  v    = (bf16*)(ws + ((size_t)48 << 20));   // (B,H,D,T)
    bf16*  mid  = (bf16*)(ws + 0);
    bf16*  o    = (bf16*)(ws + ((size_t)64 << 20));
    bf16*  h2   = (bf16*)(ws + ((size_t)80 << 20));
    bf16*  wt   = (bf16*)(ws + ((size_t)96 << 20));
    bf16*  projt = wt + (size_t)1536 * 512;
    bf16*  w1t   = wt + (size_t)2048 * 512;
    bf16*  w2t   = wt + (size_t)4096 * 512;
    float* x1    = (float*)d_out;

    // 0. all weight transposes (f32 -> bf16, [N][K])
    transpose_all<<<768, 256, 0, stream>>>(wq, wk, wv, wproj, w1, w2, wt);

    // 1. h = LN1(x)
    ln_kernel<<<BT, 256, 0, stream>>>(x, ln1g, ln1b, h);

    // 2. q|k|v = h @ wqkv  (one N=1536 GEMM; v written (B,H,D,T))
    mfma_gemm<true,  false, true ><<<dim3(12, 128), 256, 0, stream>>>(h, wt, nullptr, nullptr, q, 1536, 512);

    // 3. o = flash-attn(q,k,v) -> (B,T,C)
    attn_kernel<<<dim3(8, B_ * H_), 256, 0, stream>>>(q, k, v, o);

    // 4. x1 = x + o @ w_proj + b_proj   (x1 = d_out, f32)
    mfma_gemm<false, false, false><<<dim3(4, 128), 256, 0, stream>>>(o, projt, bproj, x, x1, 512, 512);

    // 5. h2 = LN2(x1)
    ln_kernel<<<BT, 256, 0, stream>>>(x1, ln2g, ln2b, h2);

    // 6. mid = relu(h2 @ w1 + b1)
    mfma_gemm<false, true,  true ><<<dim3(16, 128), 256, 0, stream>>>(h2, w1t, b1, nullptr, mid, 2048, 512);

    // 7. out = x1 + mid @ w2 + b2   (in-place on d_out)
    mfma_gemm<false, false, false><<<dim3(4, 128), 256, 0, stream>>>(mid, w2t, b2, x1, (float*)d_out, 512, 2048);
}